// Round 8
// baseline (407.745 us; speedup 1.0000x reference)
//
#include <hip/hip_runtime.h>
#include <hip/hip_bf16.h>

// ---- types / helpers -------------------------------------------------------
typedef __attribute__((ext_vector_type(8))) short short8;
typedef __attribute__((ext_vector_type(4))) short short4v;
typedef __attribute__((ext_vector_type(4))) float float4v;
typedef __bf16 bf16x8 __attribute__((ext_vector_type(8)));

#define MFMA16(A,B,C) __builtin_amdgcn_mfma_f32_16x16x32_bf16( \
    __builtin_bit_cast(bf16x8,(A)), __builtin_bit_cast(bf16x8,(B)), (C), 0, 0, 0)

static __device__ __forceinline__ float bf2f(unsigned short b){
  unsigned u = ((unsigned)b) << 16; float f; __builtin_memcpy(&f,&u,sizeof(f)); return f;
}
static __device__ __forceinline__ unsigned short f2bf(float f){
  unsigned u; __builtin_memcpy(&u,&f,sizeof(u));
  u = (u + 0x7FFFu + ((u>>16)&1u)) >> 16; return (unsigned short)u;
}
static __device__ __forceinline__ float siluf(float x){
  return x * __builtin_amdgcn_rcpf(1.0f + __expf(-x));
}
static __device__ __forceinline__ float ldf(const float* p, size_t i){ return p[i]; }
static __device__ __forceinline__ float ldf(const unsigned short* p, size_t i){ return bf2f(p[i]); }

// ---- generic packed-B MFMA GEMM -------------------------------------------
// flags: 1=silu, 2=bias, 4=residual(res, stride ldoF)
__global__ __launch_bounds__(256) void k_gemm(
    const unsigned short* __restrict__ A, int lda,
    const unsigned short* __restrict__ Bp, int KT, int NT,
    const float* __restrict__ bias,
    float* __restrict__ outF, int ldoF,
    unsigned short* __restrict__ outH, int ldoH,
    const float* __restrict__ res,
    int Nc, int flags)
{
  const int w = threadIdx.x >> 6, lane = threadIdx.x & 63;
  const int l15 = lane & 15, q = lane >> 4;
  const int rowL = blockIdx.x * 64 + w * 16;
  const int colB = blockIdx.y * 64;
  const short8* pa = (const short8*)(A + (size_t)(rowL + l15) * lda);
  const short8* pb = (const short8*)Bp;
  float4v acc[4] = {};
  int ntc[4];
  #pragma unroll
  for (int i = 0; i < 4; ++i){ int t = (colB >> 4) + i; ntc[i] = t < NT ? t : NT - 1; }
  for (int kt = 0; kt < KT; ++kt){
    short8 a = pa[kt * 4 + q];
    #pragma unroll
    for (int i = 0; i < 4; ++i){
      short8 b = pb[(size_t)(kt * NT + ntc[i]) * 64 + lane];
      acc[i] = MFMA16(a, b, acc[i]);
    }
  }
  const bool doB = flags & 2, doS = flags & 1, doR = flags & 4;
  #pragma unroll
  for (int i = 0; i < 4; ++i){
    int c = colB + i * 16 + l15;
    if (c >= Nc) continue;
    float bv = doB ? bias[c] : 0.0f;
    #pragma unroll
    for (int r = 0; r < 4; ++r){
      int row = rowL + q * 4 + r;
      float v = acc[i][r] + bv;
      if (doS) v = siluf(v);
      if (doR) v += res[(size_t)row * ldoF + c];
      if (outF) outF[(size_t)row * ldoF + c] = v;
      if (outH) outH[(size_t)row * ldoH + c] = f2bf(v);
    }
  }
}

// ---- weight packing into fragment order ------------------------------------
template<typename T>
static __device__ __forceinline__ void pack_tile(
    const T* W, int ldw, int Krows, int Ncols,
    unsigned short* dst, int NTtot, int ntoff, int kt, int nt,
    const float* addrow)
{
  int lane = threadIdx.x;
  int l15 = lane & 15, q = lane >> 4;
  int col = nt * 16 + l15;
  int kr0 = kt * 32 + q * 8;
  short8 v;
  #pragma unroll
  for (int j = 0; j < 8; ++j){
    int r = kr0 + j;
    float x = 0.0f;
    if (r < Krows && col < Ncols){
      x = ldf(W, (size_t)r * ldw + col);
      if (addrow) x += addrow[(r >> 5) * 256 + col];
    }
    v[j] = (short)f2bf(x);
  }
  ((short8*)dst)[(size_t)(kt * NTtot + ntoff + nt) * 64 + lane] = v;
}

// all weight packing in one launch (64-thread blocks)
__global__ void k_packW(
    const float* Ws, const float* Wn,
    const float* typeW, const float* polarW, const float* fracW,
    const float* m1W, const float* m2W, const float* a1W, const float* a2W,
    unsigned short* Wsp, unsigned short* Wnp, unsigned short* typep,
    unsigned short* polarp, unsigned short* fracp,
    unsigned short* W12p, unsigned short* W1botp, unsigned short* W2Tp,
    unsigned short* a1p, unsigned short* a2p)
{
  int b = blockIdx.x;
  if (b < 64)      { pack_tile(Ws,    256, 100, 256, Wsp,   16, 0, b >> 4, b & 15, nullptr); return; }
  if (b < 256){ int s = b - 64;  pack_tile(Wn,    256, 384, 256, Wnp,   16, 0, s >> 4, s & 15, nullptr); return; }
  if (b < 312){ int s = b - 256; pack_tile(typeW, 100, 256, 100, typep,  7, 0, s / 7,  s % 7,  nullptr); return; }
  if (b < 320){ int s = b - 312; pack_tile(polarW,  6, 256,   6, polarp, 1, 0, s, 0, nullptr); return; }
  if (b < 328){ int s = b - 320; pack_tile(fracW,   3, 256,   3, fracp,  1, 0, s, 0, nullptr); return; }
  int s2 = b - 328;                   // 3200 layer-pack blocks
  int l = s2 / 800, bb = s2 % 800;
  const float* m1Wl = m1W + (size_t)l * 578 * 256;
  const float* m2Wl = m2W + (size_t)l * 65536;
  const float* a1Wl = a1W + (size_t)l * 131072;
  const float* a2Wl = a2W + (size_t)l * 65536;
  unsigned short* W12pl   = W12p   + (size_t)l * 131072;
  unsigned short* W1botpl = W1botp + (size_t)l * 16384;
  unsigned short* W2Tpl   = W2Tp   + (size_t)l * 65536;
  unsigned short* a1pl    = a1p    + (size_t)l * 131072;
  unsigned short* a2pl    = a2p    + (size_t)l * 65536;
  if (bb < 128)       pack_tile(m1Wl,           256, 256, 256, W12pl,  32,  0, bb >> 4, bb & 15, nullptr);
  else if (bb < 256){ int s = bb - 128; pack_tile(m1Wl + 256*256, 256, 256, 256, W12pl,  32, 16, s >> 4, s & 15, nullptr); }
  else if (bb < 288){ int s = bb - 256; pack_tile(m1Wl + 512*256, 256,  64, 256, W1botpl,16,  0, s >> 4, s & 15, nullptr); }
  else if (bb < 416){ int s = bb - 288; pack_tile(m2Wl,           256, 256, 256, W2Tpl,  16,  0, s >> 4, s & 15, nullptr); }
  else if (bb < 672){ int s = bb - 416; pack_tile(a1Wl,           256, 512, 256, a1pl,   16,  0, s >> 4, s & 15, nullptr); }
  else              { int s = bb - 672; pack_tile(a2Wl,           256, 256, 256, a2pl,   16,  0, s >> 4, s & 15, nullptr); }
}

// ---- all activation preprocessing in one launch (256-thread blocks) --------
__global__ void k_prep2(const float* at, const float* t, const float* fc,
                        const float* lpol, const float* m1W, const float* m1b,
                        unsigned short* atp, unsigned short* cat1,
                        unsigned short* femb, float* lpw)
{
  int b = blockIdx.x;
  if (b < 2048){
    int id = b * 256 + threadIdx.x;
    int r = id >> 7, c = id & 127;
    atp[id] = (c < 100) ? f2bf(at[r * 100 + c]) : (unsigned short)0;
  } else if (b < 2176){
    int g = b - 2048, i = threadIdx.x;
    if (i < 128){
      float tg = t[g];
      int f = i & 63;
      float fr = __expf((-9.210340371976184f / 63.0f) * (float)f);
      float arg = tg * fr;
      float v = (i < 64) ? __sinf(arg) : __cosf(arg);
      unsigned short hv = f2bf(v);
      for (int n = 0; n < 32; ++n)
        cat1[(size_t)(g * 32 + n) * 384 + 256 + i] = hv;
    }
  } else if (b < 2688){
    int e = (b - 2176) * 256 + threadIdx.x;    // E = 131072
    int g = e >> 10, i = (e >> 5) & 31, j = e & 31;
    int nt = g * 32 + i, ns = g * 32 + j;
    unsigned short o[64];
    #pragma unroll
    for (int k = 0; k < 3; ++k){
      float d = fc[ns * 3 + k] - fc[nt * 3 + k];
      d -= floorf(d);
      #pragma unroll
      for (int f = 0; f < 10; ++f){
        float ang = d * (6.283185307179586f * (float)f);
        o[k * 10 + f]      = f2bf(__sinf(ang));
        o[30 + k * 10 + f] = f2bf(__cosf(ang));
      }
    }
    #pragma unroll
    for (int z = 60; z < 64; ++z) o[z] = 0;
    short8* dst = (short8*)(femb + (size_t)e * 64);
    #pragma unroll
    for (int v = 0; v < 8; ++v){
      short8 s;
      #pragma unroll
      for (int j2 = 0; j2 < 8; ++j2) s[j2] = (short)o[v * 8 + j2];
      dst[v] = s;
    }
  } else {
    int s = b - 2688;
    int l = s >> 7, g = s & 127, c = threadIdx.x;
    const float* W = m1W + (size_t)l * 578 * 256;
    float acc = m1b[l * 256 + c];
    #pragma unroll
    for (int k = 0; k < 6; ++k)
      acc += lpol[g * 6 + k] * W[(572 + k) * 256 + c];
    lpw[((size_t)l * 128 + g) * 256 + c] = acc;
  }
}

#define HLD 264   // LDS row stride (shorts) for 256-col bf16 tiles

// ---- LN + P12 GEMM + fragment-pack ------------------------------------------
// 256 blocks: (graph g, output half halfT).
__global__ __launch_bounds__(256) void k_lnP(
    const float* __restrict__ nf, const float* __restrict__ g_,
    const float* __restrict__ b_,
    const unsigned short* __restrict__ W12p, const float* __restrict__ lpwl,
    unsigned short* __restrict__ P1Tp, unsigned short* __restrict__ P2Tp)
{
  __shared__ unsigned short hld[32 * HLD];   // 16.9 KB
  __shared__ unsigned short PT[256 * 40];    // 20 KB
  const int w = threadIdx.x >> 6, lane = threadIdx.x & 63;
  const int l15 = lane & 15, q = lane >> 4;
  const int g = blockIdx.x >> 1, halfT = blockIdx.x & 1;
  #pragma unroll
  for (int rr = 0; rr < 8; ++rr){
    int row = w * 8 + rr;
    float4v x = *(const float4v*)(nf + ((size_t)(g*32+row))*256 + lane*4);
    float s = x[0]+x[1]+x[2]+x[3];
    #pragma unroll
    for (int m=1;m<64;m<<=1) s += __shfl_xor(s,m,64);
    float mu = s * (1.f/256.f);
    float d0=x[0]-mu,d1=x[1]-mu,d2=x[2]-mu,d3=x[3]-mu;
    float vs=d0*d0+d1*d1+d2*d2+d3*d3;
    #pragma unroll
    for (int m=1;m<64;m<<=1) vs += __shfl_xor(vs,m,64);
    float rs = rsqrtf(vs*(1.f/256.f)+1e-5f);
    float4v gg = *(const float4v*)(g_ + lane*4);
    float4v bb = *(const float4v*)(b_ + lane*4);
    short4v o;
    o[0]=(short)f2bf(d0*rs*gg[0]+bb[0]);
    o[1]=(short)f2bf(d1*rs*gg[1]+bb[1]);
    o[2]=(short)f2bf(d2*rs*gg[2]+bb[2]);
    o[3]=(short)f2bf(d3*rs*gg[3]+bb[3]);
    *(short4v*)(&hld[row*HLD + lane*4]) = o;
  }
  __syncthreads();
  float4v acc[2][4] = {};
  const short8* pb = (const short8*)W12p;
  for (int kt = 0; kt < 8; ++kt){
    short8 a0 = *(const short8*)(&hld[(size_t)l15*HLD + kt*32 + q*8]);
    short8 a1 = *(const short8*)(&hld[(size_t)(16+l15)*HLD + kt*32 + q*8]);
    #pragma unroll
    for (int i = 0; i < 4; ++i){
      short8 bfr = pb[(size_t)(kt*32 + halfT*16 + w*4 + i)*64 + lane];
      acc[0][i] = MFMA16(a0, bfr, acc[0][i]);
      acc[1][i] = MFMA16(a1, bfr, acc[1][i]);
    }
  }
  #pragma unroll
  for (int i = 0; i < 4; ++i){
    int Tl = w*4 + i;
    float lv = (halfT == 0) ? lpwl[g*256 + Tl*16 + l15] : 0.0f;
    #pragma unroll
    for (int mt = 0; mt < 2; ++mt){
      short4v o;
      #pragma unroll
      for (int r = 0; r < 4; ++r) o[r] = (short)f2bf(acc[mt][i][r] + lv);
      *(short4v*)(&PT[(size_t)(Tl*16 + l15)*40 + mt*16 + q*4]) = o;
    }
  }
  __syncthreads();
  unsigned short* dstbase = halfT ? P2Tp : P1Tp;
  #pragma unroll
  for (int s = 0; s < 4; ++s){
    int Tl = w + s*4;
    short8 v = *(const short8*)(&PT[(size_t)(Tl*16 + l15)*40 + q*8]);
    *(short8*)(dstbase + ((size_t)(g*16 + Tl)*64 + lane)*8) = v;
  }
}

// ---- fused a1+a2 epilogue MLP (256 blocks x 16 rows) ------------------------
__global__ __launch_bounds__(256) void k_a12(
    const unsigned short* __restrict__ cat2,
    const unsigned short* __restrict__ a1pl, const float* __restrict__ a1bl,
    const unsigned short* __restrict__ a2pl, const float* __restrict__ a2bl,
    float* __restrict__ nf, unsigned short* __restrict__ cat2w)
{
  __shared__ unsigned short t1[16 * HLD];   // 8.4 KB
  const int w = threadIdx.x >> 6, lane = threadIdx.x & 63;
  const int l15 = lane & 15, q = lane >> 4;
  const int r0 = blockIdx.x * 16;
  const short8* pb1 = (const short8*)a1pl;
  const short8* pb2 = (const short8*)a2pl;
  float4v acc[4] = {};
  for (int kt = 0; kt < 16; ++kt){
    short8 a0 = *(const short8*)(cat2 + (size_t)(r0 + l15)*512 + kt*32 + q*8);
    #pragma unroll
    for (int i = 0; i < 4; ++i){
      short8 bfr = pb1[(size_t)(kt*16 + w*4 + i)*64 + lane];
      acc[i] = MFMA16(a0, bfr, acc[i]);
    }
  }
  #pragma unroll
  for (int i = 0; i < 4; ++i){
    int c = (w*4+i)*16 + l15;
    float bv = a1bl[c];
    #pragma unroll
    for (int r = 0; r < 4; ++r)
      t1[(size_t)(q*4 + r)*HLD + c] = f2bf(siluf(acc[i][r] + bv));
  }
  __syncthreads();
  float4v c2[4] = {};
  for (int kt = 0; kt < 8; ++kt){
    short8 a0 = *(const short8*)(&t1[(size_t)l15*HLD + kt*32 + q*8]);
    #pragma unroll
    for (int i = 0; i < 4; ++i){
      short8 bfr = pb2[(size_t)(kt*16 + w*4 + i)*64 + lane];
      c2[i] = MFMA16(a0, bfr, c2[i]);
    }
  }
  #pragma unroll
  for (int i = 0; i < 4; ++i){
    int c = (w*4+i)*16 + l15;
    float bv = a2bl[c];
    #pragma unroll
    for (int r = 0; r < 4; ++r){
      int row = r0 + q*4 + r;
      float v = nf[(size_t)row*256 + c] + siluf(c2[i][r] + bv);
      nf[(size_t)row*256 + c] = v;
      cat2w[(size_t)row*512 + c] = f2bf(v);
    }
  }
}

// ---- final LN + graph mean --------------------------------------------------
__global__ __launch_bounds__(256) void k_lnF(
    const float* __restrict__ nf, const float* __restrict__ g_,
    const float* __restrict__ b_,
    unsigned short* __restrict__ h, unsigned short* __restrict__ gf)
{
  __shared__ unsigned short hld[32 * HLD];
  const int w = threadIdx.x >> 6, lane = threadIdx.x & 63;
  const int g = blockIdx.x;
  #pragma unroll
  for (int rr = 0; rr < 8; ++rr){
    int row = w * 8 + rr;
    float4v x = *(const float4v*)(nf + ((size_t)(g*32+row))*256 + lane*4);
    float s = x[0]+x[1]+x[2]+x[3];
    #pragma unroll
    for (int m=1;m<64;m<<=1) s += __shfl_xor(s,m,64);
    float mu = s * (1.f/256.f);
    float d0=x[0]-mu,d1=x[1]-mu,d2=x[2]-mu,d3=x[3]-mu;
    float vs=d0*d0+d1*d1+d2*d2+d3*d3;
    #pragma unroll
    for (int m=1;m<64;m<<=1) vs += __shfl_xor(vs,m,64);
    float rs = rsqrtf(vs*(1.f/256.f)+1e-5f);
    float4v gg = *(const float4v*)(g_ + lane*4);
    float4v bb = *(const float4v*)(b_ + lane*4);
    short4v o;
    o[0]=(short)f2bf(d0*rs*gg[0]+bb[0]);
    o[1]=(short)f2bf(d1*rs*gg[1]+bb[1]);
    o[2]=(short)f2bf(d2*rs*gg[2]+bb[2]);
    o[3]=(short)f2bf(d3*rs*gg[3]+bb[3]);
    *(short4v*)(&hld[row*HLD + lane*4]) = o;
    *(short4v*)(h + ((size_t)(g*32+row))*256 + lane*4) = o;
  }
  __syncthreads();
  int c = threadIdx.x;
  float s = 0.0f;
  #pragma unroll
  for (int n = 0; n < 32; ++n) s += bf2f(hld[n*HLD + c]);
  gf[g*256 + c] = f2bf(s * (1.0f/32.0f));
}

// ---- fused edge kernel v5 ---------------------------------------------------
// 2048 blocks x 4 waves; block covers 64 edges (2 target nodes), ONE barrier.
// XCD swizzle: g = b & 127 (all 16 blocks of a graph on one XCD).
// KEY: phase-2 accumulators REUSE phase-1's acc array (same registers) —
// round-7 counters showed acc+c2 as separate vars cost 128 AGPRs + 68 VGPR =
// 196 regs -> 2 blocks/CU. Reuse -> ~132 regs -> 3 blocks/CU (12 waves).
#define EST 268
__global__ __launch_bounds__(256, 3) void k_edge(
    const unsigned short* __restrict__ femb,
    const unsigned short* __restrict__ W1botp,
    const unsigned short* __restrict__ P1Tp,
    const unsigned short* __restrict__ P2Tp,
    const unsigned short* __restrict__ W2Tp,
    const float* __restrict__ b2,
    unsigned short* __restrict__ cat2)
{
  __shared__ unsigned short M1[64 * EST];   // 34.3 KB
  const int w = threadIdx.x >> 6, lane = threadIdx.x & 63;
  const int l15 = lane & 15, q = lane >> 4;
  const int b = blockIdx.x, g = b & 127;
  const int n0 = (b >> 7) * 2;
  const int ebase = g * 1024 + n0 * 32;
  const int cb = w * 64;
  const short8* fb8  = (const short8*)femb;
  const short8* w1b8 = (const short8*)W1botp;
  const short8* p1t8 = (const short8*)P1Tp;
  const short8* p2t8 = (const short8*)P2Tp;
  const short8* w2t8 = (const short8*)W2Tp;

  short8 ohj[2], ohn[2];
  #pragma unroll
  for (int p = 0; p < 2; ++p){
    int tj = p * 16 + l15;
    int tn = n0 + p;
    #pragma unroll
    for (int j = 0; j < 8; ++j){
      ohj[p][j] = (short)((q * 8 + j) == tj ? 0x3F80 : 0);
      ohn[p][j] = (short)((q * 8 + j) == tn ? 0x3F80 : 0);
    }
  }

  // ---- phase 1: M1^T[ch][e] ----
  float4v acc[4][4] = {};
  #pragma unroll
  for (int ks = 0; ks < 4; ++ks){
    short8 a[4];
    #pragma unroll
    for (int ct = 0; ct < 4; ++ct){
      int nt = w * 4 + ct;
      if (ks < 2)       a[ct] = w1b8[(size_t)(ks * 16 + nt) * 64 + lane];
      else if (ks == 2) a[ct] = p2t8[(size_t)(g * 16 + nt) * 64 + lane];
      else              a[ct] = p1t8[(size_t)(g * 16 + nt) * 64 + lane];
    }
    #pragma unroll
    for (int et = 0; et < 4; ++et){
      short8 bf;
      if (ks < 2){
        int edge = ebase + et * 16 + l15;
        bf = fb8[(size_t)edge * 8 + ks * 4 + q];
      } else if (ks == 2) bf = ohj[et & 1];
      else                bf = ohn[et >> 1];
      #pragma unroll
      for (int ct = 0; ct < 4; ++ct)
        acc[ct][et] = MFMA16(a[ct], bf, acc[ct][et]);
    }
  }
  #pragma unroll
  for (int ct = 0; ct < 4; ++ct)
    #pragma unroll
    for (int et = 0; et < 4; ++et){
      short4v sv;
      #pragma unroll
      for (int r = 0; r < 4; ++r) sv[r] = (short)f2bf(siluf(acc[ct][et][r]));
      *(short4v*)(&M1[(size_t)(et * 16 + l15) * EST + cb + ct * 16 + q * 4]) = sv;
    }
  __syncthreads();
  // ---- phase 2: M2^T — REUSE acc registers ----
  #pragma unroll
  for (int ct = 0; ct < 4; ++ct)
    #pragma unroll
    for (int et = 0; et < 4; ++et)
      acc[ct][et] = float4v{0.0f, 0.0f, 0.0f, 0.0f};
  for (int kt = 0; kt < 8; ++kt){
    short8 a[4];
    #pragma unroll
    for (int ct = 0; ct < 4; ++ct)
      a[ct] = w2t8[(size_t)(kt * 16 + w * 4 + ct) * 64 + lane];
    #pragma unroll
    for (int et = 0; et < 4; ++et){
      short8 bf = *(const short8*)(&M1[(size_t)(et * 16 + l15) * EST + kt * 32 + q * 8]);
      #pragma unroll
      for (int ct = 0; ct < 4; ++ct)
        acc[ct][et] = MFMA16(a[ct], bf, acc[ct][et]);
    }
  }
  float bv[4][4];
  #pragma unroll
  for (int ct = 0; ct < 4; ++ct)
    #pragma unroll
    for (int r = 0; r < 4; ++r) bv[ct][r] = b2[cb + ct * 16 + q * 4 + r];
  #pragma unroll
  for (int nn = 0; nn < 2; ++nn){
    #pragma unroll
    for (int ct = 0; ct < 4; ++ct){
      #pragma unroll
      for (int r = 0; r < 4; ++r){
        float v = siluf(acc[ct][2*nn][r] + bv[ct][r])
                + siluf(acc[ct][2*nn+1][r] + bv[ct][r]);
        v += __shfl_xor(v, 1, 16);
        v += __shfl_xor(v, 2, 16);
        v += __shfl_xor(v, 4, 16);
        v += __shfl_xor(v, 8, 16);
        if (l15 == 0)
          cat2[(size_t)(g * 32 + n0 + nn) * 512 + 256 + cb + ct * 16 + q * 4 + r] =
              f2bf(v * (1.0f / 32.0f));
      }
    }
  }
}

// ---- launcher --------------------------------------------------------------
extern "C" void kernel_launch(void* const* d_in, const int* in_sizes, int n_in,
                              void* d_out, int out_size, void* d_ws, size_t ws_size,
                              hipStream_t stream)
{
  const float* t      = (const float*)d_in[0];
  const float* at     = (const float*)d_in[1];
  const float* fc     = (const float*)d_in[2];
  const float* lpol   = (const float*)d_in[3];
  const float* Ws     = (const float*)d_in[5];
  const float* bs     = (const float*)d_in[6];
  const float* Wn     = (const float*)d_in[7];
  const float* bn     = (const float*)d_in[8];
  const float* ln_g   = (const float*)d_in[9];
  const float* ln_b   = (const float*)d_in[10];
  const float* m1W    = (const float*)d_in[11];
  const float* m1b    = (const float*)d_in[12];
  const float* m2W    = (const float*)d_in[13];
  const float* m2b    = (const float*)d_in[14];
  const float* a1W    = (const float*)d_in[15];
  const float* a1b    = (const float*)d_in[16];
  const float* a2W    = (const float*)d_in[17];
  const float* a2b    = (const float*)d_in[18];
  const float* flng   = (const float*)d_in[19];
  const float* flnb   = (const float*)d_in[20];
  const float* typeW  = (const float*)d_in[21];
  const float* typeb  = (const float*)d_in[22];
  const float* polarW = (const float*)d_in[23];
  const float* fracW  = (const float*)d_in[24];
  float* out = (float*)d_out;

  char* ws = (char*)d_ws;
  size_t off = 0;
  auto alloc = [&](size_t bytes) -> char* {
    char* p = ws + off; off += (bytes + 255) & ~(size_t)255; return p;
  };
  float*          nf    = (float*)         alloc((size_t)4096*256*4);
  unsigned short* cat2  = (unsigned short*)alloc((size_t)4096*512*2);
  unsigned short* h     = (unsigned short*)alloc((size_t)4096*256*2);
  unsigned short* cat1  = (unsigned short*)alloc((size_t)4096*384*2);
  unsigned short* atp   = (unsigned short*)alloc((size_t)4096*128*2);
  unsigned short* femb  = (unsigned short*)alloc((size_t)131072*64*2);
  float*          lpw   = (float*)         alloc((size_t)4*128*256*4);
  unsigned short* P1Tp  = (unsigned short*)alloc((size_t)128*16*64*8*2);
  unsigned short* P2Tp  = (unsigned short*)alloc((size_t)128*16*64*8*2);
  unsigned short* gf    = (unsigned short*)alloc((size_t)128*256*2);
  unsigned short* Wsp   = (unsigned short*)alloc((size_t)4*16*1024);
  unsigned short* Wnp   = (unsigned short*)alloc((size_t)12*16*1024);
  unsigned short* typep = (unsigned short*)alloc((size_t)8*7*1024);
  unsigned short* polarp= (unsigned short*)alloc((size_t)8*1*1024);
  unsigned short* fracp = (unsigned short*)alloc((size_t)8*1*1024);
  unsigned short* W12p  = (unsigned short*)alloc((size_t)4*131072*2);
  unsigned short* W1botp= (unsigned short*)alloc((size_t)4*16384*2);
  unsigned short* W2Tp  = (unsigned short*)alloc((size_t)4*65536*2);
  unsigned short* a1p   = (unsigned short*)alloc((size_t)4*131072*2);
  unsigned short* a2p   = (unsigned short*)alloc((size_t)4*65536*2);

  k_packW<<<dim3(3528), dim3(64), 0, stream>>>(Ws, Wn, typeW, polarW, fracW,
      m1W, m2W, a1W, a2W,
      Wsp, Wnp, typep, polarp, fracp, W12p, W1botp, W2Tp, a1p, a2p);
  k_prep2<<<dim3(3200), dim3(256), 0, stream>>>(at, t, fc, lpol, m1W, m1b,
                                                atp, cat1, femb, lpw);
  k_gemm<<<dim3(64,4), dim3(256), 0, stream>>>(atp, 128, Wsp, 4, 16, bs,
      (float*)nullptr, 0, cat1, 384, (const float*)nullptr, 256, 2);
  k_gemm<<<dim3(64,4), dim3(256), 0, stream>>>(cat1, 384, Wnp, 12, 16, bn,
      nf, 256, cat2, 512, (const float*)nullptr, 256, 2);

  for (int l = 0; l < 4; ++l){
    k_lnP<<<dim3(256), dim3(256), 0, stream>>>(nf, ln_g + l*256, ln_b + l*256,
        W12p + (size_t)l*131072, lpw + (size_t)l*32768, P1Tp, P2Tp);
    k_edge<<<dim3(2048), dim3(256), 0, stream>>>(femb, W1botp + (size_t)l*16384,
        P1Tp, P2Tp, W2Tp + (size_t)l*65536, m2b + l*256, cat2);
    k_a12<<<dim3(256), dim3(256), 0, stream>>>(cat2, a1p + (size_t)l*131072,
        a1b + l*256, a2p + (size_t)l*65536, a2b + l*256, nf, cat2);
  }

  k_lnF<<<dim3(128), dim3(256), 0, stream>>>(nf, flng, flnb, h, gf);
  // heads
  k_gemm<<<dim3(64,2), dim3(256), 0, stream>>>(h, 256, typep, 8, 7, typeb,
      out, 100, (unsigned short*)nullptr, 0, (const float*)nullptr, 100, 2);
  k_gemm<<<dim3(2,1), dim3(256), 0, stream>>>(gf, 256, polarp, 8, 1,
      (const float*)nullptr, out + 409600, 6, (unsigned short*)nullptr, 0,
      (const float*)nullptr, 6, 0);
  k_gemm<<<dim3(64,1), dim3(256), 0, stream>>>(h, 256, fracp, 8, 1,
      (const float*)nullptr, out + 410368, 3, (unsigned short*)nullptr, 0,
      (const float*)nullptr, 3, 0);
}

// Round 9
// 403.565 us; speedup vs baseline: 1.0104x; 1.0104x over previous
//
#include <hip/hip_runtime.h>
#include <hip/hip_bf16.h>

// ---- types / helpers -------------------------------------------------------
typedef __attribute__((ext_vector_type(8))) short short8;
typedef __attribute__((ext_vector_type(4))) short short4v;
typedef __attribute__((ext_vector_type(4))) float float4v;
typedef __bf16 bf16x8 __attribute__((ext_vector_type(8)));

#define MFMA16(A,B,C) __builtin_amdgcn_mfma_f32_16x16x32_bf16( \
    __builtin_bit_cast(bf16x8,(A)), __builtin_bit_cast(bf16x8,(B)), (C), 0, 0, 0)

static __device__ __forceinline__ float bf2f(unsigned short b){
  unsigned u = ((unsigned)b) << 16; float f; __builtin_memcpy(&f,&u,sizeof(f)); return f;
}
static __device__ __forceinline__ unsigned short f2bf(float f){
  unsigned u; __builtin_memcpy(&u,&f,sizeof(u));
  u = (u + 0x7FFFu + ((u>>16)&1u)) >> 16; return (unsigned short)u;
}
static __device__ __forceinline__ float siluf(float x){
  return x * __builtin_amdgcn_rcpf(1.0f + __expf(-x));
}
static __device__ __forceinline__ float ldf(const float* p, size_t i){ return p[i]; }
static __device__ __forceinline__ float ldf(const unsigned short* p, size_t i){ return bf2f(p[i]); }

// ---- generic packed-B MFMA GEMM body ---------------------------------------
// flags: 1=silu, 2=bias
static __device__ __forceinline__ void gemm_body(
    int bx, int by, int tid,
    const unsigned short* __restrict__ A, int lda,
    const unsigned short* __restrict__ Bp, int KT, int NT,
    const float* __restrict__ bias,
    float* __restrict__ outF, int ldoF,
    unsigned short* __restrict__ outH, int ldoH,
    int Nc, int flags)
{
  const int w = tid >> 6, lane = tid & 63;
  const int l15 = lane & 15, q = lane >> 4;
  const int rowL = bx * 64 + w * 16;
  const int colB = by * 64;
  const short8* pa = (const short8*)(A + (size_t)(rowL + l15) * lda);
  const short8* pb = (const short8*)Bp;
  float4v acc[4] = {};
  int ntc[4];
  #pragma unroll
  for (int i = 0; i < 4; ++i){ int t = (colB >> 4) + i; ntc[i] = t < NT ? t : NT - 1; }
  for (int kt = 0; kt < KT; ++kt){
    short8 a = pa[kt * 4 + q];
    #pragma unroll
    for (int i = 0; i < 4; ++i){
      short8 b = pb[(size_t)(kt * NT + ntc[i]) * 64 + lane];
      acc[i] = MFMA16(a, b, acc[i]);
    }
  }
  const bool doB = flags & 2, doS = flags & 1;
  #pragma unroll
  for (int i = 0; i < 4; ++i){
    int c = colB + i * 16 + l15;
    if (c >= Nc) continue;
    float bv = doB ? bias[c] : 0.0f;
    #pragma unroll
    for (int r = 0; r < 4; ++r){
      int row = rowL + q * 4 + r;
      float v = acc[i][r] + bv;
      if (doS) v = siluf(v);
      if (outF) outF[(size_t)row * ldoF + c] = v;
      if (outH) outH[(size_t)row * ldoH + c] = f2bf(v);
    }
  }
}

__global__ __launch_bounds__(256) void k_gemm(
    const unsigned short* __restrict__ A, int lda,
    const unsigned short* __restrict__ Bp, int KT, int NT,
    const float* __restrict__ bias,
    float* __restrict__ outF, int ldoF,
    unsigned short* __restrict__ outH, int ldoH,
    int Nc, int flags)
{
  gemm_body(blockIdx.x, blockIdx.y, threadIdx.x, A, lda, Bp, KT, NT, bias,
            outF, ldoF, outH, ldoH, Nc, flags);
}

// ---- all three output heads in one launch -----------------------------------
__global__ __launch_bounds__(256) void k_heads(
    const unsigned short* __restrict__ h, const unsigned short* __restrict__ gf,
    const unsigned short* __restrict__ typep, const float* __restrict__ typeb,
    const unsigned short* __restrict__ polarp, const unsigned short* __restrict__ fracp,
    float* __restrict__ out)
{
  int b = blockIdx.x;
  if (b < 128)
    gemm_body(b & 63, b >> 6, threadIdx.x, h, 256, typep, 8, 7, typeb,
              out, 100, (unsigned short*)nullptr, 0, 100, 2);
  else if (b < 130)
    gemm_body(b - 128, 0, threadIdx.x, gf, 256, polarp, 8, 1, (const float*)nullptr,
              out + 409600, 6, (unsigned short*)nullptr, 0, 6, 0);
  else
    gemm_body(b - 130, 0, threadIdx.x, h, 256, fracp, 8, 1, (const float*)nullptr,
              out + 410368, 3, (unsigned short*)nullptr, 0, 3, 0);
}

// ---- weight packing into fragment order ------------------------------------
template<typename T>
static __device__ __forceinline__ void pack_tile(
    int lane, const T* W, int ldw, int Krows, int Ncols,
    unsigned short* dst, int NTtot, int ntoff, int kt, int nt,
    const float* addrow)
{
  int l15 = lane & 15, q = lane >> 4;
  int col = nt * 16 + l15;
  int kr0 = kt * 32 + q * 8;
  short8 v;
  #pragma unroll
  for (int j = 0; j < 8; ++j){
    int r = kr0 + j;
    float x = 0.0f;
    if (r < Krows && col < Ncols){
      x = ldf(W, (size_t)r * ldw + col);
      if (addrow) x += addrow[(r >> 5) * 256 + col];
    }
    v[j] = (short)f2bf(x);
  }
  ((short8*)dst)[(size_t)(kt * NTtot + ntoff + nt) * 64 + lane] = v;
}

// ---- ALL setup: weight packing + activation prep in one launch --------------
// b<882: pack tiles (4 per 256-thr block, 3528 tiles total)
// else: b2=b-882: <2048 pad at; <2176 time; <2688 femb; else lpw
__global__ void k_setup(
    const float* Ws, const float* Wn, const float* typeW, const float* polarW,
    const float* fracW, const float* m1W, const float* m2W, const float* a1W,
    const float* a2W, const float* at, const float* t, const float* fc,
    const float* lpol, const float* m1b,
    unsigned short* Wsp, unsigned short* Wnp, unsigned short* typep,
    unsigned short* polarp, unsigned short* fracp,
    unsigned short* W12p, unsigned short* W1botp, unsigned short* W2Tp,
    unsigned short* a1p, unsigned short* a2p,
    unsigned short* atp, unsigned short* cat1, unsigned short* femb, float* lpw)
{
  int b = blockIdx.x;
  if (b < 882){
    int s = b * 4 + (threadIdx.x >> 6);
    if (s >= 3528) return;
    int lane = threadIdx.x & 63;
    if (s < 64)      { pack_tile(lane, Ws,    256, 100, 256, Wsp,   16, 0, s >> 4, s & 15, nullptr); return; }
    if (s < 256){ int u = s - 64;  pack_tile(lane, Wn,    256, 384, 256, Wnp,   16, 0, u >> 4, u & 15, nullptr); return; }
    if (s < 312){ int u = s - 256; pack_tile(lane, typeW, 100, 256, 100, typep,  7, 0, u / 7,  u % 7,  nullptr); return; }
    if (s < 320){ int u = s - 312; pack_tile(lane, polarW,  6, 256,   6, polarp, 1, 0, u, 0, nullptr); return; }
    if (s < 328){ int u = s - 320; pack_tile(lane, fracW,   3, 256,   3, fracp,  1, 0, u, 0, nullptr); return; }
    int s2 = s - 328;
    int l = s2 / 800, bb = s2 % 800;
    const float* m1Wl = m1W + (size_t)l * 578 * 256;
    const float* m2Wl = m2W + (size_t)l * 65536;
    const float* a1Wl = a1W + (size_t)l * 131072;
    const float* a2Wl = a2W + (size_t)l * 65536;
    unsigned short* W12pl   = W12p   + (size_t)l * 131072;
    unsigned short* W1botpl = W1botp + (size_t)l * 16384;
    unsigned short* W2Tpl   = W2Tp   + (size_t)l * 65536;
    unsigned short* a1pl    = a1p    + (size_t)l * 131072;
    unsigned short* a2pl    = a2p    + (size_t)l * 65536;
    if (bb < 128)       pack_tile(lane, m1Wl,           256, 256, 256, W12pl,  32,  0, bb >> 4, bb & 15, nullptr);
    else if (bb < 256){ int u = bb - 128; pack_tile(lane, m1Wl + 256*256, 256, 256, 256, W12pl,  32, 16, u >> 4, u & 15, nullptr); }
    else if (bb < 288){ int u = bb - 256; pack_tile(lane, m1Wl + 512*256, 256,  64, 256, W1botpl,16,  0, u >> 4, u & 15, nullptr); }
    else if (bb < 416){ int u = bb - 288; pack_tile(lane, m2Wl,           256, 256, 256, W2Tpl,  16,  0, u >> 4, u & 15, nullptr); }
    else if (bb < 672){ int u = bb - 416; pack_tile(lane, a1Wl,           256, 512, 256, a1pl,   16,  0, u >> 4, u & 15, nullptr); }
    else              { int u = bb - 672; pack_tile(lane, a2Wl,           256, 256, 256, a2pl,   16,  0, u >> 4, u & 15, nullptr); }
    return;
  }
  int b2 = b - 882;
  if (b2 < 2048){
    int id = b2 * 256 + threadIdx.x;
    int r = id >> 7, c = id & 127;
    atp[id] = (c < 100) ? f2bf(at[r * 100 + c]) : (unsigned short)0;
  } else if (b2 < 2176){
    int g = b2 - 2048, i = threadIdx.x;
    if (i < 128){
      float tg = t[g];
      int f = i & 63;
      float fr = __expf((-9.210340371976184f / 63.0f) * (float)f);
      float arg = tg * fr;
      float v = (i < 64) ? __sinf(arg) : __cosf(arg);
      unsigned short hv = f2bf(v);
      for (int n = 0; n < 32; ++n)
        cat1[(size_t)(g * 32 + n) * 384 + 256 + i] = hv;
    }
  } else if (b2 < 2688){
    int e = (b2 - 2176) * 256 + threadIdx.x;    // E = 131072
    int g = e >> 10, i = (e >> 5) & 31, j = e & 31;
    int nt = g * 32 + i, ns = g * 32 + j;
    unsigned short o[64];
    #pragma unroll
    for (int k = 0; k < 3; ++k){
      float d = fc[ns * 3 + k] - fc[nt * 3 + k];
      d -= floorf(d);
      #pragma unroll
      for (int f = 0; f < 10; ++f){
        float ang = d * (6.283185307179586f * (float)f);
        o[k * 10 + f]      = f2bf(__sinf(ang));
        o[30 + k * 10 + f] = f2bf(__cosf(ang));
      }
    }
    #pragma unroll
    for (int z = 60; z < 64; ++z) o[z] = 0;
    short8* dst = (short8*)(femb + (size_t)e * 64);
    #pragma unroll
    for (int v = 0; v < 8; ++v){
      short8 s;
      #pragma unroll
      for (int j2 = 0; j2 < 8; ++j2) s[j2] = (short)o[v * 8 + j2];
      dst[v] = s;
    }
  } else {
    int s = b2 - 2688;
    int l = s >> 7, g = s & 127, c = threadIdx.x;
    const float* W = m1W + (size_t)l * 578 * 256;
    float acc = m1b[l * 256 + c];
    #pragma unroll
    for (int k = 0; k < 6; ++k)
      acc += lpol[g * 6 + k] * W[(572 + k) * 256 + c];
    lpw[((size_t)l * 128 + g) * 256 + c] = acc;
  }
}

#define HLD 264   // LDS row stride (shorts) for 256-col bf16 tiles

// ---- LN + P12 GEMM + fragment-pack ------------------------------------------
// 256 blocks: (graph g, output half halfT).
__global__ __launch_bounds__(256) void k_lnP(
    const float* __restrict__ nf, const float* __restrict__ g_,
    const float* __restrict__ b_,
    const unsigned short* __restrict__ W12p, const float* __restrict__ lpwl,
    unsigned short* __restrict__ P1Tp, unsigned short* __restrict__ P2Tp)
{
  __shared__ unsigned short hld[32 * HLD];   // 16.9 KB
  __shared__ unsigned short PT[256 * 40];    // 20 KB
  const int w = threadIdx.x >> 6, lane = threadIdx.x & 63;
  const int l15 = lane & 15, q = lane >> 4;
  const int g = blockIdx.x >> 1, halfT = blockIdx.x & 1;
  #pragma unroll
  for (int rr = 0; rr < 8; ++rr){
    int row = w * 8 + rr;
    float4v x = *(const float4v*)(nf + ((size_t)(g*32+row))*256 + lane*4);
    float s = x[0]+x[1]+x[2]+x[3];
    #pragma unroll
    for (int m=1;m<64;m<<=1) s += __shfl_xor(s,m,64);
    float mu = s * (1.f/256.f);
    float d0=x[0]-mu,d1=x[1]-mu,d2=x[2]-mu,d3=x[3]-mu;
    float vs=d0*d0+d1*d1+d2*d2+d3*d3;
    #pragma unroll
    for (int m=1;m<64;m<<=1) vs += __shfl_xor(vs,m,64);
    float rs = rsqrtf(vs*(1.f/256.f)+1e-5f);
    float4v gg = *(const float4v*)(g_ + lane*4);
    float4v bb = *(const float4v*)(b_ + lane*4);
    short4v o;
    o[0]=(short)f2bf(d0*rs*gg[0]+bb[0]);
    o[1]=(short)f2bf(d1*rs*gg[1]+bb[1]);
    o[2]=(short)f2bf(d2*rs*gg[2]+bb[2]);
    o[3]=(short)f2bf(d3*rs*gg[3]+bb[3]);
    *(short4v*)(&hld[row*HLD + lane*4]) = o;
  }
  __syncthreads();
  float4v acc[2][4] = {};
  const short8* pb = (const short8*)W12p;
  for (int kt = 0; kt < 8; ++kt){
    short8 a0 = *(const short8*)(&hld[(size_t)l15*HLD + kt*32 + q*8]);
    short8 a1 = *(const short8*)(&hld[(size_t)(16+l15)*HLD + kt*32 + q*8]);
    #pragma unroll
    for (int i = 0; i < 4; ++i){
      short8 bfr = pb[(size_t)(kt*32 + halfT*16 + w*4 + i)*64 + lane];
      acc[0][i] = MFMA16(a0, bfr, acc[0][i]);
      acc[1][i] = MFMA16(a1, bfr, acc[1][i]);
    }
  }
  #pragma unroll
  for (int i = 0; i < 4; ++i){
    int Tl = w*4 + i;
    float lv = (halfT == 0) ? lpwl[g*256 + Tl*16 + l15] : 0.0f;
    #pragma unroll
    for (int mt = 0; mt < 2; ++mt){
      short4v o;
      #pragma unroll
      for (int r = 0; r < 4; ++r) o[r] = (short)f2bf(acc[mt][i][r] + lv);
      *(short4v*)(&PT[(size_t)(Tl*16 + l15)*40 + mt*16 + q*4]) = o;
    }
  }
  __syncthreads();
  unsigned short* dstbase = halfT ? P2Tp : P1Tp;
  #pragma unroll
  for (int s = 0; s < 4; ++s){
    int Tl = w + s*4;
    short8 v = *(const short8*)(&PT[(size_t)(Tl*16 + l15)*40 + q*8]);
    *(short8*)(dstbase + ((size_t)(g*16 + Tl)*64 + lane)*8) = v;
  }
}

// ---- fused a1+a2 epilogue MLP (256 blocks x 16 rows) ------------------------
__global__ __launch_bounds__(256) void k_a12(
    const unsigned short* __restrict__ cat2,
    const unsigned short* __restrict__ a1pl, const float* __restrict__ a1bl,
    const unsigned short* __restrict__ a2pl, const float* __restrict__ a2bl,
    float* __restrict__ nf, unsigned short* __restrict__ cat2w)
{
  __shared__ unsigned short t1[16 * HLD];   // 8.4 KB
  const int w = threadIdx.x >> 6, lane = threadIdx.x & 63;
  const int l15 = lane & 15, q = lane >> 4;
  const int r0 = blockIdx.x * 16;
  const short8* pb1 = (const short8*)a1pl;
  const short8* pb2 = (const short8*)a2pl;
  float4v acc[4] = {};
  for (int kt = 0; kt < 16; ++kt){
    short8 a0 = *(const short8*)(cat2 + (size_t)(r0 + l15)*512 + kt*32 + q*8);
    #pragma unroll
    for (int i = 0; i < 4; ++i){
      short8 bfr = pb1[(size_t)(kt*16 + w*4 + i)*64 + lane];
      acc[i] = MFMA16(a0, bfr, acc[i]);
    }
  }
  #pragma unroll
  for (int i = 0; i < 4; ++i){
    int c = (w*4+i)*16 + l15;
    float bv = a1bl[c];
    #pragma unroll
    for (int r = 0; r < 4; ++r)
      t1[(size_t)(q*4 + r)*HLD + c] = f2bf(siluf(acc[i][r] + bv));
  }
  __syncthreads();
  float4v c2[4] = {};
  for (int kt = 0; kt < 8; ++kt){
    short8 a0 = *(const short8*)(&t1[(size_t)l15*HLD + kt*32 + q*8]);
    #pragma unroll
    for (int i = 0; i < 4; ++i){
      short8 bfr = pb2[(size_t)(kt*16 + w*4 + i)*64 + lane];
      c2[i] = MFMA16(a0, bfr, c2[i]);
    }
  }
  #pragma unroll
  for (int i = 0; i < 4; ++i){
    int c = (w*4+i)*16 + l15;
    float bv = a2bl[c];
    #pragma unroll
    for (int r = 0; r < 4; ++r){
      int row = r0 + q*4 + r;
      float v = nf[(size_t)row*256 + c] + siluf(c2[i][r] + bv);
      nf[(size_t)row*256 + c] = v;
      cat2w[(size_t)row*512 + c] = f2bf(v);
    }
  }
}

// ---- final LN + graph mean --------------------------------------------------
__global__ __launch_bounds__(256) void k_lnF(
    const float* __restrict__ nf, const float* __restrict__ g_,
    const float* __restrict__ b_,
    unsigned short* __restrict__ h, unsigned short* __restrict__ gf)
{
  __shared__ unsigned short hld[32 * HLD];
  const int w = threadIdx.x >> 6, lane = threadIdx.x & 63;
  const int g = blockIdx.x;
  #pragma unroll
  for (int rr = 0; rr < 8; ++rr){
    int row = w * 8 + rr;
    float4v x = *(const float4v*)(nf + ((size_t)(g*32+row))*256 + lane*4);
    float s = x[0]+x[1]+x[2]+x[3];
    #pragma unroll
    for (int m=1;m<64;m<<=1) s += __shfl_xor(s,m,64);
    float mu = s * (1.f/256.f);
    float d0=x[0]-mu,d1=x[1]-mu,d2=x[2]-mu,d3=x[3]-mu;
    float vs=d0*d0+d1*d1+d2*d2+d3*d3;
    #pragma unroll
    for (int m=1;m<64;m<<=1) vs += __shfl_xor(vs,m,64);
    float rs = rsqrtf(vs*(1.f/256.f)+1e-5f);
    float4v gg = *(const float4v*)(g_ + lane*4);
    float4v bb = *(const float4v*)(b_ + lane*4);
    short4v o;
    o[0]=(short)f2bf(d0*rs*gg[0]+bb[0]);
    o[1]=(short)f2bf(d1*rs*gg[1]+bb[1]);
    o[2]=(short)f2bf(d2*rs*gg[2]+bb[2]);
    o[3]=(short)f2bf(d3*rs*gg[3]+bb[3]);
    *(short4v*)(&hld[row*HLD + lane*4]) = o;
    *(short4v*)(h + ((size_t)(g*32+row))*256 + lane*4) = o;
  }
  __syncthreads();
  int c = threadIdx.x;
  float s = 0.0f;
  #pragma unroll
  for (int n = 0; n < 32; ++n) s += bf2f(hld[n*HLD + c]);
  gf[g*256 + c] = f2bf(s * (1.0f/32.0f));
}

// ---- fused edge kernel v6 ---------------------------------------------------
// 2048 blocks x 8 waves (512 thr); block covers 64 edges (2 target nodes).
// Each wave: 2 ct x 4 et = 32 accumulators (half of v5) -> ~102 unified regs
// under the (512,2) 128-reg budget -> 16 waves/CU (2 blocks), 2x occupancy.
// Phase-2 first MFMA uses a fresh zero C operand (no separate zero-init) and
// a sched_barrier after __syncthreads keeps phase-2 out of phase-1's ranges.
// XCD swizzle: g = b & 127 (all 16 blocks of a graph on one XCD).
#define EST 268
__global__ __launch_bounds__(512, 2) void k_edge(
    const unsigned short* __restrict__ femb,
    const unsigned short* __restrict__ W1botp,
    const unsigned short* __restrict__ P1Tp,
    const unsigned short* __restrict__ P2Tp,
    const unsigned short* __restrict__ W2Tp,
    const float* __restrict__ b2,
    unsigned short* __restrict__ cat2)
{
  __shared__ unsigned short M1[64 * EST];   // 34.3 KB
  const int w = threadIdx.x >> 6, lane = threadIdx.x & 63;
  const int l15 = lane & 15, q = lane >> 4;
  const int b = blockIdx.x, g = b & 127;
  const int n0 = (b >> 7) * 2;
  const int ebase = g * 1024 + n0 * 32;
  const int cb = w * 32;                    // wave's 32-channel chunk (2 ct tiles)
  const short8* fb8  = (const short8*)femb;
  const short8* w1b8 = (const short8*)W1botp;
  const short8* p1t8 = (const short8*)P1Tp;
  const short8* p2t8 = (const short8*)P2Tp;
  const short8* w2t8 = (const short8*)W2Tp;

  short8 ohj[2], ohn[2];
  #pragma unroll
  for (int p = 0; p < 2; ++p){
    int tj = p * 16 + l15;
    int tn = n0 + p;
    #pragma unroll
    for (int j = 0; j < 8; ++j){
      ohj[p][j] = (short)((q * 8 + j) == tj ? 0x3F80 : 0);
      ohn[p][j] = (short)((q * 8 + j) == tn ? 0x3F80 : 0);
    }
  }

  // ---- phase 1: M1^T[ch][e] ----
  float4v acc[2][4] = {};
  #pragma unroll
  for (int ks = 0; ks < 4; ++ks){
    short8 a[2];
    #pragma unroll
    for (int ct = 0; ct < 2; ++ct){
      int nt = w * 2 + ct;
      if (ks < 2)       a[ct] = w1b8[(size_t)(ks * 16 + nt) * 64 + lane];
      else if (ks == 2) a[ct] = p2t8[(size_t)(g * 16 + nt) * 64 + lane];
      else              a[ct] = p1t8[(size_t)(g * 16 + nt) * 64 + lane];
    }
    #pragma unroll
    for (int et = 0; et < 4; ++et){
      short8 bf;
      if (ks < 2){
        int edge = ebase + et * 16 + l15;
        bf = fb8[(size_t)edge * 8 + ks * 4 + q];
      } else if (ks == 2) bf = ohj[et & 1];
      else                bf = ohn[et >> 1];
      #pragma unroll
      for (int ct = 0; ct < 2; ++ct)
        acc[ct][et] = MFMA16(a[ct], bf, acc[ct][et]);
    }
  }
  #pragma unroll
  for (int ct = 0; ct < 2; ++ct)
    #pragma unroll
    for (int et = 0; et < 4; ++et){
      short4v sv;
      #pragma unroll
      for (int r = 0; r < 4; ++r) sv[r] = (short)f2bf(siluf(acc[ct][et][r]));
      *(short4v*)(&M1[(size_t)(et * 16 + l15) * EST + cb + ct * 16 + q * 4]) = sv;
    }
  __syncthreads();
  __builtin_amdgcn_sched_barrier(0);
  // ---- phase 2: M2^T — acc reused, first kt peeled (C = fresh zero) ----
  {
    const float4v z = {0.0f, 0.0f, 0.0f, 0.0f};
    short8 a[2];
    #pragma unroll
    for (int ct = 0; ct < 2; ++ct)
      a[ct] = w2t8[(size_t)(0 * 16 + w * 2 + ct) * 64 + lane];
    #pragma unroll
    for (int et = 0; et < 4; ++et){
      short8 bf = *(const short8*)(&M1[(size_t)(et * 16 + l15) * EST + 0 + q * 8]);
      #pragma unroll
      for (int ct = 0; ct < 2; ++ct)
        acc[ct][et] = MFMA16(a[ct], bf, z);
    }
  }
  for (int kt = 1; kt < 8; ++kt){
    short8 a[2];
    #pragma unroll
    for (int ct = 0; ct < 2; ++ct)
      a[ct] = w2t8[(size_t)(kt * 16 + w * 2 + ct) * 64 + lane];
    #pragma unroll
    for (int et = 0; et < 4; ++et){
      short8 bf = *(const short8*)(&M1[(size_t)(et * 16 + l15) * EST + kt * 32 + q * 8]);
      #pragma unroll
      for (int ct = 0; ct < 2; ++ct)
        acc[ct][et] = MFMA16(a[ct], bf, acc[ct][et]);
    }
  }
  float bv[2][4];
  #pragma unroll
  for (int ct = 0; ct < 2; ++ct)
    #pragma unroll
    for (int r = 0; r < 4; ++r) bv[ct][r] = b2[cb + ct * 16 + q * 4 + r];
  #pragma unroll
  for (int nn = 0; nn < 2; ++nn){
    #pragma unroll
    for (int ct = 0; ct < 2; ++ct){
      #pragma unroll
      for (int r = 0; r < 4; ++r){
        float v = siluf(acc[ct][2*nn][r] + bv[ct][r])
                + siluf(acc[ct][2*nn+1][r] + bv[ct][r]);
        v += __shfl_xor(v, 1, 16);
        v += __shfl_xor(v, 2, 16);
        v += __shfl_xor(v, 4, 16);
        v += __shfl_xor(v, 8, 16);
        if (l15 == 0)
          cat2[(size_t)(g * 32 + n0 + nn) * 512 + 256 + cb + ct * 16 + q * 4 + r] =
              f2bf(v * (1.0f / 32.0f));
      }
    }
  }
}

// ---- launcher --------------------------------------------------------------
extern "C" void kernel_launch(void* const* d_in, const int* in_sizes, int n_in,
                              void* d_out, int out_size, void* d_ws, size_t ws_size,
                              hipStream_t stream)
{
  const float* t      = (const float*)d_in[0];
  const float* at     = (const float*)d_in[1];
  const float* fc     = (const float*)d_in[2];
  const float* lpol   = (const float*)d_in[3];
  const float* Ws     = (const float*)d_in[5];
  const float* bs     = (const float*)d_in[6];
  const float* Wn     = (const float*)d_in[7];
  const float* bn     = (const float*)d_in[8];
  const float* ln_g   = (const float*)d_in[9];
  const float* ln_b   = (const float*)d_in[10];
  const float* m1W    = (const float*)d_in[11];
  const float* m1b    = (const float*)d_in[12];
  const float* m2W    = (const float*)d_in[13];
  const float* m2b    = (const float*)d_in[14];
  const float* a1W    = (const float*)d_in[15];
  const float* a1b    = (const float*)d_in[16];
  const float* a2W    = (const float*)d_in[17];
  const float* a2b    = (const float*)d_in[18];
  const float* flng   = (const float*)d_in[19];
  const float* flnb   = (const float*)d_in[20];
  const float* typeW  = (const float*)d_in[21];
  const float* typeb  = (const float*)d_in[22];
  const float* polarW = (const float*)d_in[23];
  const float* fracW  = (const float*)d_in[24];
  float* out = (float*)d_out;

  char* ws = (char*)d_ws;
  size_t off = 0;
  auto alloc = [&](size_t bytes) -> char* {
    char* p = ws + off; off += (bytes + 255) & ~(size_t)255; return p;
  };
  float*          nf    = (float*)         alloc((size_t)4096*256*4);
  unsigned short* cat2  = (unsigned short*)alloc((size_t)4096*512*2);
  unsigned short* h     = (unsigned short*)alloc((size_t)4096*256*2);
  unsigned short* cat1  = (unsigned short*)alloc((size_t)4096*384*2);
  unsigned short* atp   = (unsigned short*)alloc((size_t)4096*128*2);
  unsigned short* femb  = (unsigned short*)alloc((size_t)131072*64*2);
  float*          lpw   = (float*)         alloc((size_t)4*128*256*4);
  unsigned short* P1Tp  = (unsigned short*)alloc((size_t)128*16*64*8*2);
  unsigned short* P2Tp  = (unsigned short*)alloc((size_t)128*16*64*8*2);
  unsigned short* gf    = (unsigned short*)alloc((size_t)128*256*2);
  unsigned short* Wsp   = (unsigned short*)alloc((size_t)4*16*1024);
  unsigned short* Wnp   = (unsigned short*)alloc((size_t)12*16*1024);
  unsigned short* typep = (unsigned short*)alloc((size_t)8*7*1024);
  unsigned short* polarp= (unsigned short*)alloc((size_t)8*1*1024);
  unsigned short* fracp = (unsigned short*)alloc((size_t)8*1*1024);
  unsigned short* W12p  = (unsigned short*)alloc((size_t)4*131072*2);
  unsigned short* W1botp= (unsigned short*)alloc((size_t)4*16384*2);
  unsigned short* W2Tp  = (unsigned short*)alloc((size_t)4*65536*2);
  unsigned short* a1p   = (unsigned short*)alloc((size_t)4*131072*2);
  unsigned short* a2p   = (unsigned short*)alloc((size_t)4*65536*2);

  k_setup<<<dim3(4082), dim3(256), 0, stream>>>(Ws, Wn, typeW, polarW, fracW,
      m1W, m2W, a1W, a2W, at, t, fc, lpol, m1b,
      Wsp, Wnp, typep, polarp, fracp, W12p, W1botp, W2Tp, a1p, a2p,
      atp, cat1, femb, lpw);
  k_gemm<<<dim3(64,4), dim3(256), 0, stream>>>(atp, 128, Wsp, 4, 16, bs,
      (float*)nullptr, 0, cat1, 384, 256, 2);
  k_gemm<<<dim3(64,4), dim3(256), 0, stream>>>(cat1, 384, Wnp, 12, 16, bn,
      nf, 256, cat2, 512, 256, 2);

  for (int l = 0; l < 4; ++l){
    k_lnP<<<dim3(256), dim3(256), 0, stream>>>(nf, ln_g + l*256, ln_b + l*256,
        W12p + (size_t)l*131072, lpw + (size_t)l*32768, P1Tp, P2Tp);
    k_edge<<<dim3(2048), dim3(512), 0, stream>>>(femb, W1botp + (size_t)l*16384,
        P1Tp, P2Tp, W2Tp + (size_t)l*65536, m2b + l*256, cat2);
    k_a12<<<dim3(256), dim3(256), 0, stream>>>(cat2, a1p + (size_t)l*131072,
        a1b + l*256, a2p + (size_t)l*65536, a2b + l*256, nf, cat2);
  }

  k_lnF<<<dim3(128), dim3(256), 0, stream>>>(nf, flng, flnb, h, gf);
  k_heads<<<dim3(194), dim3(256), 0, stream>>>(h, gf, typep, typeb, polarp, fracp, out);
}